// Round 4
// baseline (312.265 us; speedup 1.0000x reference)
//
#include <hip/hip_runtime.h>

typedef unsigned short u16;
typedef unsigned int u32;
typedef __attribute__((ext_vector_type(8))) short bf16x8;
typedef __attribute__((ext_vector_type(4))) float f32x4;
typedef __attribute__((ext_vector_type(2))) unsigned int u32x2;

#define LOG2E 1.4426950408889634f

__device__ __forceinline__ u16 f2bf(float f) {
    u32 u = __float_as_uint(f);
    u += 0x7fffu + ((u >> 16) & 1u);
    return (u16)(u >> 16);
}
// pack two f32 -> two truncated bf16 in one v_perm (hi in bits 31:16, lo in 15:0)
__device__ __forceinline__ u32 pk_bf_trunc(float hi, float lo) {
    return __builtin_amdgcn_perm(__float_as_uint(hi), __float_as_uint(lo), 0x07060302u);
}

// ---------------- Kernel 0: weight prep ----------------
__global__ void wconv_kernel(const float* __restrict__ Wq, const float* __restrict__ Wk,
                             const float* __restrict__ Wv, const float* __restrict__ Wg,
                             const float* __restrict__ Wo, const float* __restrict__ norm_w,
                             const float* __restrict__ norm_b, const float* __restrict__ bg,
                             u16* __restrict__ wbf, float* __restrict__ cvec) {
    int b = blockIdx.x;
    if (b < 64) {
        int idx = b * 256 + threadIdx.x;  // 0..16383
        float w = norm_w[idx & 127];
        wbf[0 * 16384 + idx] = f2bf(Wq[idx] * w);
        wbf[1 * 16384 + idx] = f2bf(Wk[idx] * w);
        wbf[2 * 16384 + idx] = f2bf(Wv[idx] * w);
        wbf[3 * 16384 + idx] = f2bf(Wg[idx] * w);
        wbf[4 * 16384 + idx] = f2bf(Wo[idx]);
    } else {
        int m = b - 64;
        int n = threadIdx.x;
        if (n < 128) {
            const float* W = (m == 0) ? Wq : (m == 1) ? Wk : (m == 2) ? Wv : Wg;
            float c = 0.f;
#pragma unroll
            for (int k4 = 0; k4 < 32; ++k4) {
                f32x4 bb = *(const f32x4*)&norm_b[k4 * 4];
                f32x4 ww = *(const f32x4*)&W[n * 128 + k4 * 4];
                c += bb[0] * ww[0] + bb[1] * ww[1] + bb[2] * ww[2] + bb[3] * ww[3];
            }
            if (m == 3) c += bg[n];
            cvec[m * 128 + n] = c;
        }
    }
}

// ---------------- Kernel 0.5: LayerNorm + head-bias precompute ----------------
// Grid 1600, 512 threads, 64 rows/block. Writes Xbf (bf16 normalized pair) and
// biasT[(l*4+h)*320+j] = Wb[h]·pair[l][j] (raw). Both live in d_out (dead until outproj).
// XCD-grouped so slab l is produced on XCD l&7 (matches attn's consumer mapping).
__global__ __launch_bounds__(512)
void ln_kernel(const float* __restrict__ pair, const float* __restrict__ Wb,
               u16* __restrict__ Xbf, float* __restrict__ biasT) {
    const int bid = blockIdx.x;
    const int xcd = bid & 7;
    const int s = bid >> 3;        // 0..199
    const int jc = s % 5;
    const int l = (s / 5) * 8 + xcd;
    const int j0 = jc * 64;
    const int tid = threadIdx.x;
    const int row_g = tid >> 3;    // 0..63
    const int c8 = tid & 7;

    const size_t row = (size_t)(l * 320 + j0 + row_g);
    const float* prow = pair + row * 128 + c8 * 16;
    f32x4 pr[4];
#pragma unroll
    for (int u = 0; u < 4; ++u) pr[u] = *(const f32x4*)(prow + u * 4);

    float s1 = 0.f, s2 = 0.f;
    float bd[4] = {0.f, 0.f, 0.f, 0.f};
#pragma unroll
    for (int u = 0; u < 4; ++u) {
        f32x4 p = pr[u];
        s1 += p[0] + p[1] + p[2] + p[3];
        s2 += p[0] * p[0] + p[1] * p[1] + p[2] * p[2] + p[3] * p[3];
#pragma unroll
        for (int hh = 0; hh < 4; ++hh) {
            f32x4 w4 = *(const f32x4*)&Wb[hh * 128 + c8 * 16 + u * 4];
            bd[hh] += p[0] * w4[0] + p[1] * w4[1] + p[2] * w4[2] + p[3] * w4[3];
        }
    }
    s1 += __shfl_xor(s1, 1); s1 += __shfl_xor(s1, 2); s1 += __shfl_xor(s1, 4);
    s2 += __shfl_xor(s2, 1); s2 += __shfl_xor(s2, 2); s2 += __shfl_xor(s2, 4);
#pragma unroll
    for (int hh = 0; hh < 4; ++hh) {
        bd[hh] += __shfl_xor(bd[hh], 1);
        bd[hh] += __shfl_xor(bd[hh], 2);
        bd[hh] += __shfl_xor(bd[hh], 4);
    }
    float mu = s1 * 0.0078125f;
    float var = s2 * 0.0078125f - mu * mu;
    float rs = rsqrtf(var + 1e-5f);

#pragma unroll
    for (int u = 0; u < 4; ++u) {
        f32x4 p = pr[u];
        ushort4 xv;
        xv.x = f2bf((p[0] - mu) * rs);
        xv.y = f2bf((p[1] - mu) * rs);
        xv.z = f2bf((p[2] - mu) * rs);
        xv.w = f2bf((p[3] - mu) * rs);
        *(ushort4*)&Xbf[row * 128 + c8 * 16 + u * 4] = xv;
    }
    if (c8 < 4) biasT[((size_t)l * 4 + c8) * 320 + j0 + row_g] = bd[c8];
}

// ---------------- Kernel 1: fused projection + attention (LN pre-done) ----------------
// Grid 1280 = (l, h), XCD-grouped (l&7 = XCD). 512 threads / 8 waves.
// LDS 51.2 KB + bias 1.25 KB -> 3 blocks/CU (24 waves, 75% occupancy).
// smem u16 layout:
//   [0, 5120)      : per-wave Q-transpose bufs (8 x 640)
//   [5120, 15360)  : Ks 320x32, 16B-unit swizzle u' = u ^ ((j>>2)&3)
//   [15360, 25600) : VTs 32x320, 16B-unit low3 swizzle u' = u ^ (dv&7)
// Phase A is barrier-free (A-frags straight from global Xbf); ONE barrier total.
#define PB_OFF 0
#define KS_OFF 5120
#define VTS_OFF 15360

__global__ __launch_bounds__(512, 6)
void attn_kernel(const u16* __restrict__ Xbf,
                 const float* __restrict__ biasT,
                 const u16* __restrict__ wbf,
                 const float* __restrict__ cvec,
                 u16* __restrict__ Obf,
                 u16* __restrict__ Gg) {
    const int bid = blockIdx.x;
    const int xcd = bid & 7;
    const int s_i = bid >> 3;
    const int h = s_i & 3;
    const int l = ((s_i >> 2) << 3) | xcd;
    const int tid = threadIdx.x;
    const int wave = tid >> 6;
    const int lane = tid & 63;
    const int i_lo = lane & 15;
    const int q = lane >> 4;

    __shared__ __align__(16) u16 smem[25600];
    __shared__ __align__(16) float biasLds[320];  // bias[j] * log2e

    const int wrow = (wave & 3) * 16;  // MFMA row strip within tile
    const int nth_flip = wave >> 2;    // wave does Q,K on tiles with t&1 == wave>>2

    if (tid < 320) biasLds[tid] = biasT[((size_t)l * 4 + h) * 320 + tid] * LOG2E;

    // folded biases for this lane's output channels (halves 0/1)
    float cQ[2], cK[2], cV[2], cG[2];
#pragma unroll
    for (int half = 0; half < 2; ++half) {
        int n = h * 32 + half * 16 + i_lo;
        cQ[half] = cvec[0 * 128 + n];
        cK[half] = cvec[1 * 128 + n];
        cV[half] = cvec[2 * 128 + n];
        cG[half] = cvec[3 * 128 + n];
    }

    u32 qkeep[3][4];  // per-strip Q fragment, packed bf16

    // ---------- Phase A: projections, 5 tiles of 64 rows, NO barriers ----------
#pragma unroll 1
    for (int t = 0; t < 5; ++t) {
        const int j0 = t * 64;
        // A-fragments straight from global Xbf
        bf16x8 xf[4];
#pragma unroll
        for (int kc = 0; kc < 4; ++kc)
            xf[kc] = *(const bf16x8*)&Xbf[((size_t)(l * 320 + j0 + wrow + i_lo)) * 128 +
                                          kc * 32 + q * 8];

        const int nth = (t & 1) ^ nth_flip;
        f32x4 acc[4];
#pragma unroll
        for (int n2 = 0; n2 < 4; ++n2) acc[n2] = (f32x4){0.f, 0.f, 0.f, 0.f};
#pragma unroll
        for (int kc = 0; kc < 4; ++kc) {
#pragma unroll
            for (int n2 = 0; n2 < 4; ++n2) {
                int nt = nth * 4 + n2;  // 0,1=Q 2,3=K 4,5=V 6,7=G
                bf16x8 wf = *(const bf16x8*)&wbf[(nt >> 1) * 16384 +
                                                 (h * 32 + (nt & 1) * 16 + i_lo) * 128 + kc * 32 + q * 8];
                acc[n2] = __builtin_amdgcn_mfma_f32_16x16x32_bf16(xf[kc], wf, acc[n2], 0, 0, 0);
            }
        }
        const int jrow = j0 + wrow + q * 4;
        if (nth == 0) {
            const int ti = t >> 1;  // strip index for this wave
#pragma unroll
            for (int dd = 0; dd < 2; ++dd)
#pragma unroll
                for (int rr = 0; rr < 2; ++rr)
                    qkeep[ti][dd * 2 + rr] =
                        (u32)f2bf(acc[dd][rr * 2] + cQ[dd]) |
                        ((u32)f2bf(acc[dd][rr * 2 + 1] + cQ[dd]) << 16);
            // K[j][d], swizzled: unit u = 2*(n2&1) + (i_lo>>3); u' = u ^ q  ((j>>2)&3 == q here)
#pragma unroll
            for (int n2 = 2; n2 < 4; ++n2) {
                const int uK = (2 * (n2 & 1) + (i_lo >> 3)) ^ q;
#pragma unroll
                for (int r = 0; r < 4; ++r)
                    smem[KS_OFF + (jrow + r) * 32 + uK * 8 + (i_lo & 7)] =
                        f2bf(acc[n2][r] + cK[n2 & 1]);
            }
        } else {
            // V^T[dv][j], swizzled: unit u = j>>3; u' low3 ^= (dv&7) = (i_lo&7)
#pragma unroll
            for (int n2 = 0; n2 < 2; ++n2) {
                const int dv = n2 * 16 + i_lo;
#pragma unroll
                for (int r = 0; r < 4; ++r) {
                    const int j = jrow + r;
                    const int uu = j >> 3;
                    const int uh = (uu & ~7) | ((uu & 7) ^ (i_lo & 7));
                    smem[VTS_OFF + dv * 320 + uh * 8 + (j & 7)] =
                        f2bf(acc[n2][r] + cV[n2]);
                }
            }
#pragma unroll
            for (int n2 = 2; n2 < 4; ++n2)
#pragma unroll
                for (int r = 0; r < 4; ++r) {
                    float z = acc[n2][r] + cG[n2 & 1];
                    float g = 1.0f / (1.0f + exp2f(-z * LOG2E));
                    Gg[((size_t)((l * 4 + h) * 320 + jrow + r)) * 32 + (n2 & 1) * 16 + i_lo] = f2bf(g);
                }
        }
    }
    __syncthreads();  // the ONLY barrier: Ks/VTs/bias/Gg visible

    // ---------- Phase B: wave w handles strips w, w+8, w+16(w<4) ----------
    const float SC = 0.17677669529663687f * LOG2E;  // Dh^-0.5 * log2e
    const f32x4 zero4 = {0.f, 0.f, 0.f, 0.f};
    u16* pb = smem + PB_OFF + wave * 640;
    const int nstrip = (wave < 4) ? 3 : 2;
    const int kswz = (q ^ (i_lo >> 2)) * 8;          // Ks read swizzle (per-lane const)
    const int la4 = (((lane & 16) << 1) | i_lo) * 4; // bpermute src A (bytes)
    const int lb4 = la4 + 64;                        // bpermute src B
    const bool hi = (lane >= 32);
#pragma unroll 1
    for (int t2 = 0; t2 < nstrip; ++t2) {
        const int i0 = (wave + 8 * t2) * 16;

        // gate prefetch at strip top: same-XCD L2 hit, hidden under 5 chunks of compute
        const size_t gbase = ((size_t)((l * 4 + h) * 320 + i0 + i_lo)) * 32;
        u32x2 gv0 = *(const u32x2*)&Gg[gbase + 0 * 16 + q * 4];
        u32x2 gv1 = *(const u32x2*)&Gg[gbase + 1 * 16 + q * 4];

        // Q transpose: C-layout regs -> pb[i][d] (stride 40) -> B-frag read
#pragma unroll
        for (int dd = 0; dd < 2; ++dd)
#pragma unroll
            for (int rr = 0; rr < 2; ++rr) {
                u32 v = qkeep[t2][dd * 2 + rr];
                pb[(q * 4 + rr * 2) * 40 + dd * 16 + i_lo] = (u16)v;
                pb[(q * 4 + rr * 2 + 1) * 40 + dd * 16 + i_lo] = (u16)(v >> 16);
            }
        bf16x8 qf = *(const bf16x8*)&pb[i_lo * 40 + q * 8];

        f32x4 oacc[2];
        oacc[0] = zero4; oacc[1] = zero4;
        float sum = 0.f;
#pragma unroll 1
        for (int c = 0; c < 5; ++c) {
            // QK^T: S^T = K * Q^T (swizzled Ks reads)
            f32x4 sc4[4];
#pragma unroll
            for (int jt = 0; jt < 4; ++jt) {
                bf16x8 kf = *(const bf16x8*)&smem[KS_OFF + (c * 64 + jt * 16 + i_lo) * 32 + kswz];
                sc4[jt] = __builtin_amdgcn_mfma_f32_16x16x32_bf16(kf, qf, zero4, 0, 0, 0);
            }
            // softmax numerator + row-sum accumulation
#pragma unroll
            for (int jt = 0; jt < 4; ++jt) {
                f32x4 b4 = *(const f32x4*)&biasLds[c * 64 + jt * 16 + q * 4];
#pragma unroll
                for (int r = 0; r < 4; ++r) {
                    float p = exp2f(sc4[jt][r] * SC + b4[r]);
                    sc4[jt][r] = p;
                    sum += p;
                }
            }
            // pack P rows to bf16 pairs
            u32 pkx[4], pky[4];
#pragma unroll
            for (int jt = 0; jt < 4; ++jt) {
                pkx[jt] = pk_bf_trunc(sc4[jt][1], sc4[jt][0]);
                pky[jt] = pk_bf_trunc(sc4[jt][3], sc4[jt][2]);
            }
            __builtin_amdgcn_s_setprio(1);
            // P transpose in-register via ds_bpermute (no LDS round-trip), then PV
#pragma unroll
            for (int kt2 = 0; kt2 < 2; ++kt2) {
                const int jA = 2 * kt2, jB = jA + 1;
                u32 a0 = (u32)__builtin_amdgcn_ds_bpermute(la4, (int)pkx[jA]);
                u32 b0 = (u32)__builtin_amdgcn_ds_bpermute(la4, (int)pkx[jB]);
                u32 a1 = (u32)__builtin_amdgcn_ds_bpermute(la4, (int)pky[jA]);
                u32 b1 = (u32)__builtin_amdgcn_ds_bpermute(la4, (int)pky[jB]);
                u32 a2 = (u32)__builtin_amdgcn_ds_bpermute(lb4, (int)pkx[jA]);
                u32 b2 = (u32)__builtin_amdgcn_ds_bpermute(lb4, (int)pkx[jB]);
                u32 a3 = (u32)__builtin_amdgcn_ds_bpermute(lb4, (int)pky[jA]);
                u32 b3 = (u32)__builtin_amdgcn_ds_bpermute(lb4, (int)pky[jB]);
                union { bf16x8 v; u32 u[4]; } pf;
                pf.u[0] = hi ? b0 : a0;
                pf.u[1] = hi ? b1 : a1;
                pf.u[2] = hi ? b2 : a2;
                pf.u[3] = hi ? b3 : a3;
                const int vswz = ((4 * kt2 + q) ^ (i_lo & 7)) * 8;
#pragma unroll
                for (int mt = 0; mt < 2; ++mt) {
                    bf16x8 vf = *(const bf16x8*)&smem[VTS_OFF + (mt * 16 + i_lo) * 320 +
                                                      c * 64 + vswz];
                    oacc[mt] = __builtin_amdgcn_mfma_f32_16x16x32_bf16(vf, pf.v, oacc[mt], 0, 0, 0);
                }
            }
            __builtin_amdgcn_s_setprio(0);
        }

        sum += __shfl_xor(sum, 16);
        sum += __shfl_xor(sum, 32);
        float rinv = 1.0f / sum;
        // lane holds O^T[d = mt*16+q*4+r][i = i0+i_lo]; normalize, gate, store
#pragma unroll
        for (int mt = 0; mt < 2; ++mt) {
            u32x2 gv = mt ? gv1 : gv0;
            float g0 = __uint_as_float(gv.x << 16);
            float g1 = __uint_as_float(gv.x & 0xffff0000u);
            float g2 = __uint_as_float(gv.y << 16);
            float g3 = __uint_as_float(gv.y & 0xffff0000u);
            u32x2 pk;
            pk.x = pk_bf_trunc(oacc[mt][1] * rinv * g1, oacc[mt][0] * rinv * g0);
            pk.y = pk_bf_trunc(oacc[mt][3] * rinv * g3, oacc[mt][2] * rinv * g2);
            *(u32x2*)&Obf[((size_t)(l * 320 + i0 + i_lo)) * 128 + h * 32 + mt * 16 + q * 4] = pk;
        }
    }
}

// ---------------- Kernel 2: out = pair + Og @ Wo^T + bo  (Og pre-gated in attn) ----------------
__global__ __launch_bounds__(256, 4)
void outproj_kernel(const float* __restrict__ pair,
                    const float* __restrict__ bo,
                    const u16* __restrict__ Obf,
                    const u16* __restrict__ wbf,
                    float* __restrict__ out) {
    const int tid = threadIdx.x;
    const int wave = tid >> 6;
    const int lane = tid & 63;
    const int i_lo = lane & 15;
    const int q = lane >> 4;

    __shared__ __align__(16) u16 WoLds[128 * 128];  // 16B unit u of row n stored at u ^ (n&15)

    const int row0 = blockIdx.x * 64 + wave * 16;  // 16-row strip per wave

    // issue gated-O fragment loads first (HBM latency hides under Wo staging + barrier)
    bf16x8 of[4];
#pragma unroll
    for (int kc = 0; kc < 4; ++kc)
        of[kc] = *(const bf16x8*)&Obf[((size_t)(row0 + i_lo)) * 128 + kc * 32 + q * 8];

    const u16* Wo = wbf + 4 * 16384;
#pragma unroll
    for (int it = 0; it < 8; ++it) {
        int unit = it * 256 + tid;  // 2048 units of 8 u16 (16 B)
        int n = unit >> 4, k8 = unit & 15;
        *(bf16x8*)&WoLds[n * 128 + ((k8 ^ (n & 15)) * 8)] = *(const bf16x8*)&Wo[unit * 8];
    }
    __syncthreads();

    f32x4 acc[8];
#pragma unroll
    for (int nt = 0; nt < 8; ++nt) acc[nt] = (f32x4){0.f, 0.f, 0.f, 0.f};
#pragma unroll
    for (int nt = 0; nt < 8; ++nt) {
#pragma unroll
        for (int kc = 0; kc < 4; ++kc) {
            bf16x8 wf = *(const bf16x8*)&WoLds[(nt * 16 + i_lo) * 128 + (((kc * 4 + q) ^ i_lo) * 8)];
            acc[nt] = __builtin_amdgcn_mfma_f32_16x16x32_bf16(wf, of[kc], acc[nt], 0, 0, 0);
        }
    }
#pragma unroll
    for (int nt = 0; nt < 8; ++nt) {
        size_t idx = ((size_t)(row0 + i_lo)) * 128 + nt * 16 + q * 4;
        f32x4 p4 = *(const f32x4*)&pair[idx];
        f32x4 b4 = *(const f32x4*)&bo[nt * 16 + q * 4];
        f32x4 o4;
        o4[0] = acc[nt][0] + p4[0] + b4[0];
        o4[1] = acc[nt][1] + p4[1] + b4[1];
        o4[2] = acc[nt][2] + p4[2] + b4[2];
        o4[3] = acc[nt][3] + p4[3] + b4[3];
        *(f32x4*)&out[idx] = o4;
    }
}

extern "C" void kernel_launch(void* const* d_in, const int* in_sizes, int n_in,
                              void* d_out, int out_size, void* d_ws, size_t ws_size,
                              hipStream_t stream) {
    const float* pair   = (const float*)d_in[0];
    const float* norm_w = (const float*)d_in[1];
    const float* norm_b = (const float*)d_in[2];
    const float* Wq     = (const float*)d_in[3];
    const float* Wk     = (const float*)d_in[4];
    const float* Wv     = (const float*)d_in[5];
    const float* Wg     = (const float*)d_in[6];
    const float* bg     = (const float*)d_in[7];
    const float* Wo     = (const float*)d_in[8];
    const float* bo     = (const float*)d_in[9];
    const float* Wb     = (const float*)d_in[10];

    u16* wbf    = (u16*)d_ws;                   // 5 * 128*128 bf16 weights
    float* cvec = (float*)(wbf + 5 * 16384);    // 512 f32 folded biases
    u16* Obf    = (u16*)(cvec + 512);           // 102400 x 128 bf16 (gated, normalized)
    u16* Gg     = Obf + (size_t)102400 * 128;   // (l,h,i,d) 1280 x 320 x 32 bf16 gates
    float* out  = (float*)d_out;

    // Xbf + biasT live INSIDE d_out (52.4 MB): dead until outproj overwrites it.
    u16* Xbf     = (u16*)d_out;                           // 26.2 MB
    float* biasT = (float*)((char*)d_out + 26214400);     // +1.6 MB  (total 27.85 < 52.4)

    wconv_kernel<<<68, 256, 0, stream>>>(Wq, Wk, Wv, Wg, Wo, norm_w, norm_b, bg, wbf, cvec);
    ln_kernel<<<1600, 512, 0, stream>>>(pair, Wb, Xbf, biasT);
    attn_kernel<<<320 * 4, 512, 0, stream>>>(Xbf, biasT, wbf, cvec, Obf, Gg);
    outproj_kernel<<<1600, 256, 0, stream>>>(pair, bo, Obf, wbf, out);
}